// Round 6
// baseline (260.459 us; speedup 1.0000x reference)
//
#include <hip/hip_runtime.h>

#define T_FULL 4096
#define D 128
#define K 1024
#define NVEC 65536           // 16*4096
#define BDT 8388608          // 16*128*4096
#define BT 128               // tokens per block (4 waves x 32)
#define NBLK (NVEC / BT)     // 512 blocks -> exactly 2 blocks/CU
#define KG 16                // codes per register group
#define NG (K / KG)          // 64 groups
#define PLANE_B (K * D * 2)  // 262144 bytes per f16 plane
#define GSTRIDE (KG * 256)   // 4096 bytes per group within a plane

typedef _Float16 f16x8 __attribute__((ext_vector_type(8)));
typedef float f32x4 __attribute__((ext_vector_type(4)));

#define MFMA(a, b, c) __builtin_amdgcn_mfma_f32_16x16x32_f16((a), (b), (c), 0, 0, 0)

// ---------------- prep: zero ws + ee norms + (2e) 2-way fp16 split planes ----------------
__global__ __launch_bounds__(128) void prep_kernel(const float* __restrict__ cb,
    float* __restrict__ ee, _Float16* __restrict__ E1, _Float16* __restrict__ E2,
    unsigned int* __restrict__ counts, unsigned int* __restrict__ done,
    float* __restrict__ loss_acc) {
  int k = blockIdx.x, d = threadIdx.x;
  if (d == 0) {
    counts[k] = 0u;
    if (k == 0) { *done = 0u; *loss_acc = 0.f; }
  }
  float e = cb[k * D + d];
  float v = e * e;
#pragma unroll
  for (int o = 32; o > 0; o >>= 1) v += __shfl_down(v, o, 64);
  __shared__ float tmp[2];
  if ((d & 63) == 0) tmp[d >> 6] = v;
  __syncthreads();
  if (d == 0) ee[k] = tmp[0] + tmp[1];

  float s = 2.0f * e;                       // fold the -2*dot scale (exact)
  _Float16 h1 = (_Float16)s;                // RTN: |s-h1| <= 2^-11 |s|
  _Float16 h2 = (_Float16)(s - (float)h1);  // residual <= 2^-22 |s|
  E1[k * D + d] = h1;
  E2[k * D + d] = h2;
}

// ---------------- main: A-in-regs (fp16 2-split), B DIRECT L2->regs, 3-term MFMA --------
// R6: barrier-free K-loop. The E planes (512 KB) are L2-resident (read by all
// 512 blocks); LDS staging + per-tile __syncthreads (vmcnt(0)+lgkmcnt(0) drain)
// was pure sync overhead. Each wave double-buffers 16-code B groups in
// registers via global_load_dwordx4; the bits are identical to the old
// staged/de-swizzled path: lane(c,q) reads E_p[g*16+c][dims (dc*4+q)*8..+8].
// Grid is 512 blocks = 2/CU -> occupancy is capped at 2 waves/SIMD no matter
// what, so amdgpu_waves_per_eu(2,2) pins the register allocator there
// (R4 lesson: without the cap the RA chases 4 waves/EU and spills).
// Verification: VGPR 160-220, FETCH ~34 MB, WRITE ~37.5 MB (no spill).
__global__ __launch_bounds__(256)
__attribute__((amdgpu_waves_per_eu(2, 2)))
void vq_main(
    const float* __restrict__ inp, const float* __restrict__ cb,
    const float* __restrict__ ee, const _Float16* __restrict__ Eplanes,
    unsigned int* __restrict__ counts, unsigned int* __restrict__ done,
    float* __restrict__ loss_acc, float* __restrict__ out) {
  __shared__ float ee_sh[K];                              // 4 KB
  __shared__ int   midx[BT];
  __shared__ float lred[4];
  __shared__ int   lastf;

  float* out_q   = out + 1;
  float* out_idx = out + 2 + BDT;

  const int tid  = threadIdx.x;
  const int lane = tid & 63;
  const int w    = tid >> 6;        // wave 0..3: owns tokens w*32..w*32+31
  const int c    = lane & 15;       // MFMA col (code) / token within 16
  const int q    = lane >> 4;       // quad
  const int b    = blockIdx.x >> 5;
  const int t0   = (blockIdx.x & 31) * BT;

  // per-lane B base: code row c (256 B/row), dim-chunk q (16 B)
  const char* E1p = (const char*)Eplanes + c * 256 + q * 16;
  const char* E2p = E1p + PLANE_B;

  // --- X -> registers, exact 2-way fp16 split (A-fragment layout) ---
  f16x8 A1[2][4], A2[2][4];
  {
    const float* xin = inp + (size_t)b * D * T_FULL + t0 + w * 32 + c;
#pragma unroll
    for (int n = 0; n < 2; ++n)
#pragma unroll
      for (int dc = 0; dc < 4; ++dc) {
        f16x8 a1, a2;
#pragma unroll
        for (int j = 0; j < 8; ++j) {
          int d = dc * 32 + q * 8 + j;
          float x = xin[(size_t)d * T_FULL + n * 16];
          _Float16 h1 = (_Float16)x;
          _Float16 h2 = (_Float16)(x - (float)h1);
          a1[j] = h1; a2[j] = h2;
        }
        A1[n][dc] = a1; A2[n][dc] = a2;
      }
  }
  // --- ee -> LDS ---
#pragma unroll
  for (int i = tid; i < K; i += 256) ee_sh[i] = ee[i];
  __syncthreads();           // last barrier before the epilogue

  float bv[2][4];
  int   bi[2][4];
#pragma unroll
  for (int n = 0; n < 2; ++n)
#pragma unroll
    for (int r = 0; r < 4; ++r) { bv[n][r] = 3.4e38f; bi[n][r] = 0; }

  // --- register double-buffered B groups; NO barriers, NO LDS in this loop ---
  f16x8 B1a[4], B2a[4], B1b[4], B2b[4];

#define LOADG(S, g)                                                            \
  do {                                                                         \
    const char* _p1 = E1p + (size_t)(g) * GSTRIDE;                             \
    const char* _p2 = E2p + (size_t)(g) * GSTRIDE;                             \
    _Pragma("unroll")                                                          \
    for (int dc = 0; dc < 4; ++dc) {                                           \
      B1##S[dc] = *(const f16x8*)(_p1 + dc * 64);                              \
      B2##S[dc] = *(const f16x8*)(_p2 + dc * 64);                              \
    }                                                                          \
  } while (0)

#define COMPG(S, g)                                                            \
  do {                                                                         \
    f32x4 accM[2], accC[2];                                                    \
    accM[0] = (f32x4){0.f, 0.f, 0.f, 0.f};                                     \
    accM[1] = (f32x4){0.f, 0.f, 0.f, 0.f};                                     \
    accC[0] = (f32x4){0.f, 0.f, 0.f, 0.f};                                     \
    accC[1] = (f32x4){0.f, 0.f, 0.f, 0.f};                                     \
    _Pragma("unroll")                                                          \
    for (int dc = 0; dc < 4; ++dc) {                                           \
      _Pragma("unroll")                                                        \
      for (int n = 0; n < 2; ++n) {                                            \
        accM[n] = MFMA(A1[n][dc], B1##S[dc], accM[n]);  /* x2*e2 dropped */    \
        f32x4 t_ = accC[n];                                                    \
        t_ = MFMA(A1[n][dc], B2##S[dc], t_);                                   \
        t_ = MFMA(A2[n][dc], B1##S[dc], t_);                                   \
        accC[n] = t_;                                                          \
      }                                                                        \
    }                                                                          \
    const int   code = (g) * KG + c;                                           \
    const float eev  = ee_sh[code];                                            \
    _Pragma("unroll")                                                          \
    for (int n = 0; n < 2; ++n)                                                \
      _Pragma("unroll")                                                        \
      for (int r = 0; r < 4; ++r) {                                            \
        float dist = eev - accM[n][r] - accC[n][r];                            \
        if (dist < bv[n][r]) { bv[n][r] = dist; bi[n][r] = code; }             \
      }                                                                        \
  } while (0)

  LOADG(a, 0);
  for (int gg = 0; gg < NG / 2; ++gg) {
    LOADG(b, 2 * gg + 1);
    COMPG(a, 2 * gg);
    if (gg < NG / 2 - 1) LOADG(a, 2 * gg + 2);
    COMPG(b, 2 * gg + 1);
  }
#undef LOADG
#undef COMPG

  // --- cross-lane argmin over the 16 code-cols (tie -> smaller idx) ---
#pragma unroll
  for (int m = 1; m <= 8; m <<= 1)
#pragma unroll
    for (int n = 0; n < 2; ++n)
#pragma unroll
      for (int r = 0; r < 4; ++r) {
        float ov = __shfl_xor(bv[n][r], m, 64);
        int   oi = __shfl_xor(bi[n][r], m, 64);
        if (ov < bv[n][r] || (ov == bv[n][r] && oi < bi[n][r])) {
          bv[n][r] = ov; bi[n][r] = oi;
        }
      }
  if (c == 0) {
#pragma unroll
    for (int n = 0; n < 2; ++n)
#pragma unroll
      for (int r = 0; r < 4; ++r)
        midx[w * 32 + n * 16 + q * 4 + r] = bi[n][r];
  }
  __syncthreads();

  if (tid < BT) {
    int ki = midx[tid];
    out_idx[(size_t)b * T_FULL + t0 + tid] = (float)ki;
    atomicAdd(&counts[ki], 1u);
  }

  // --- coalesced epilogue (R0 pattern): thread=token, full-line q stores ---
  float lsum = 0.f;
  {
    const int t  = tid & 127;
    const int dh = tid >> 7;            // d-half: 0..63 / 64..127
    const int kq = midx[t];
    const float* crow = cb + (size_t)kq * D + dh * 64;
    const float* xrow = inp + ((size_t)b * D + dh * 64) * T_FULL + t0 + t;
    float*       qrow = out_q + ((size_t)b * D + dh * 64) * T_FULL + t0 + t;
#pragma unroll
    for (int dd = 0; dd < 64; dd += 4) {
      float4 qv = *(const float4*)(crow + dd);
      float x0 = xrow[(size_t)(dd + 0) * T_FULL];
      float x1 = xrow[(size_t)(dd + 1) * T_FULL];
      float x2 = xrow[(size_t)(dd + 2) * T_FULL];
      float x3 = xrow[(size_t)(dd + 3) * T_FULL];
      float df;
      df = qv.x - x0; lsum = fmaf(df, df, lsum); qrow[(size_t)(dd + 0) * T_FULL] = qv.x;
      df = qv.y - x1; lsum = fmaf(df, df, lsum); qrow[(size_t)(dd + 1) * T_FULL] = qv.y;
      df = qv.z - x2; lsum = fmaf(df, df, lsum); qrow[(size_t)(dd + 2) * T_FULL] = qv.z;
      df = qv.w - x3; lsum = fmaf(df, df, lsum); qrow[(size_t)(dd + 3) * T_FULL] = qv.w;
    }
  }
#pragma unroll
  for (int o = 32; o > 0; o >>= 1) lsum += __shfl_down(lsum, o, 64);
  if (lane == 0) lred[w] = lsum;
  __syncthreads();
  if (tid == 0) {
    atomicAdd(loss_acc, lred[0] + lred[1] + lred[2] + lred[3]);
    __threadfence();                                   // publish before ticket
    unsigned ticket = atomicAdd(done, 1u);
    lastf = (ticket == NBLK - 1) ? 1 : 0;
  }
  __syncthreads();

  // --- last block: finalize loss + perplexity ---
  if (lastf) {
    __threadfence();
    float ent = 0.f;
#pragma unroll
    for (int i = tid; i < K; i += 256) {
      float cnt = (float)atomicAdd(&counts[i], 0u);    // coherent read
      float p = cnt * (1.0f / (float)NVEC);
      ent = fmaf(p, logf(p + 1e-10f), ent);
    }
#pragma unroll
    for (int o = 32; o > 0; o >>= 1) ent += __shfl_down(ent, o, 64);
    if (lane == 0) lred[w] = ent;
    __syncthreads();
    if (tid == 0) {
      float e = lred[0] + lred[1] + lred[2] + lred[3];
      float l = atomicAdd(loss_acc, 0.f);
      out[0]       = 0.25f * (l / (float)BDT);
      out[1 + BDT] = expf(-e);
    }
  }
}

extern "C" void kernel_launch(void* const* d_in, const int* in_sizes, int n_in,
                              void* d_out, int out_size, void* d_ws, size_t ws_size,
                              hipStream_t stream) {
  const float* inp = (const float*)d_in[0];   // [16,128,4096] fp32
  const float* cb  = (const float*)d_in[1];   // [1024,128] fp32
  float* out = (float*)d_out;                 // [loss | q(BDT) | perp | idx(B*T)]

  char* ws = (char*)d_ws;
  unsigned int* counts  = (unsigned int*)ws;                // 4 KB
  unsigned int* done    = (unsigned int*)(ws + 4096);
  float*        lossacc = (float*)(ws + 4160);
  float*        ee      = (float*)(ws + 8192);              // 4 KB
  _Float16*     E1      = (_Float16*)(ws + 12288);          // 256 KB
  _Float16*     E2      = (_Float16*)(ws + 12288 + PLANE_B);// 256 KB

  prep_kernel<<<K, 128, 0, stream>>>(cb, ee, E1, E2, counts, done, lossacc);
  vq_main<<<NBLK, 256, 0, stream>>>(inp, cb, ee, E1, counts, done, lossacc, out);
}

// Round 7
// 207.289 us; speedup vs baseline: 1.2565x; 1.2565x over previous
//
#include <hip/hip_runtime.h>

#define T_FULL 4096
#define D 128
#define K 1024
#define NVEC 65536           // 16*4096
#define BDT 8388608          // 16*128*4096
#define BT 64                // tokens per block
#define NBLK (NVEC / BT)     // 1024 blocks -> 4 blocks/CU
#define KH 512               // codes per wave-pair (half)
#define KT 16                // codes per staged tile (per half)
#define NIT (KH / KT)        // 32 iterations
#define PLANE_B (K * D * 2)  // 262144 bytes per f16 plane
#define HTILE_B (2 * KT * D * 2)  // 8192 bytes per staged tile (2 planes)
#define TPLANE (KT * D * 2)       // 4096: plane stride inside a tile
#define GTILE (KT * D * 2)        // 4096: global stride per tile within a plane

typedef _Float16 f16x8 __attribute__((ext_vector_type(8)));
typedef float f32x4 __attribute__((ext_vector_type(4)));

#define MFMA(a, b, c) __builtin_amdgcn_mfma_f32_16x16x32_f16((a), (b), (c), 0, 0, 0)

#define GLOAD_LDS(g, l)                                                        \
  __builtin_amdgcn_global_load_lds(                                            \
      (const __attribute__((address_space(1))) unsigned int*)(g),              \
      (__attribute__((address_space(3))) unsigned int*)(l), 16, 0, 0)

// ---------------- prep: zero ws + ee norms + (2e) 2-way fp16 split planes ----------------
__global__ __launch_bounds__(128) void prep_kernel(const float* __restrict__ cb,
    float* __restrict__ ee, _Float16* __restrict__ E1, _Float16* __restrict__ E2,
    unsigned int* __restrict__ counts, unsigned int* __restrict__ done,
    float* __restrict__ loss_acc) {
  int k = blockIdx.x, d = threadIdx.x;
  if (d == 0) {
    counts[k] = 0u;
    if (k == 0) { *done = 0u; *loss_acc = 0.f; }
  }
  float e = cb[k * D + d];
  float v = e * e;
#pragma unroll
  for (int o = 32; o > 0; o >>= 1) v += __shfl_down(v, o, 64);
  __shared__ float tmp[2];
  if ((d & 63) == 0) tmp[d >> 6] = v;
  __syncthreads();
  if (d == 0) ee[k] = tmp[0] + tmp[1];

  float s = 2.0f * e;                       // fold the -2*dot scale (exact)
  _Float16 h1 = (_Float16)s;                // RTN: |s-h1| <= 2^-11 |s|
  _Float16 h2 = (_Float16)(s - (float)h1);  // residual <= 2^-22 |s|
  E1[k * D + d] = h1;
  E2[k * D + d] = h2;
}

// ---------------- main: in-block code-split for 4 waves/SIMD at R0 intensity ----------------
// R7: block = 64 tokens x 1024 codes, 4 waves. Waves 0,1 own codes 0..511;
// waves 2,3 own codes 512..1023; EVERY wave keeps 32 tokens (n=2), so the
// per-MFMA ds_read/staging ratios are identical to R0 (R2's intensity loss
// avoided) while per-wave serial work halves. Grid 1024 = 4 blocks/CU and
// LDS ~38 KB -> 16 waves/CU = 4 waves/SIMD (2x R0's TLP). Each code-half has
// its own KT=16 double-buffer staged by its own 2 waves (same XOR swizzle).
// Argmin merges in-block via LDS (half 0 = lower indices -> tie keeps ref
// first-min semantics). Chained single-acc MFMA = bit-identical to R0.
// amdgpu_waves_per_eu(4,4) pins the RA at the 128-VGPR cap (R3/R4 lessons);
// body needs ~119. Spill tripwire: FETCH ~34-40 MB, WRITE ~37.5 MB.
__global__ __launch_bounds__(256)
__attribute__((amdgpu_waves_per_eu(4, 4)))
void vq_main(
    const float* __restrict__ inp, const float* __restrict__ cb,
    const float* __restrict__ ee, const _Float16* __restrict__ Eplanes,
    unsigned int* __restrict__ counts, unsigned int* __restrict__ done,
    float* __restrict__ loss_acc, float* __restrict__ out) {
  __shared__ __align__(16) _Float16 Bs[2 * 2 * KT * D * 2]; // [half][buf][8KB] = 32 KB
  __shared__ float ee_sh[K];                                // 4 KB
  __shared__ float mval[2][BT];                             // per-half best dist
  __shared__ int   mi[2][BT];                               // per-half best idx
  __shared__ int   midx[BT];
  __shared__ float lred[4];
  __shared__ int   lastf;

  float* out_q   = out + 1;
  float* out_idx = out + 2 + BDT;

  const int tid  = threadIdx.x;
  const int lane = tid & 63;
  const int w    = tid >> 6;        // wave 0..3
  const int h    = w >> 1;          // code-half 0/1
  const int tw   = (w & 1) * 32;    // wave's token offset within block
  const int c    = lane & 15;       // MFMA col (code) / token within 16
  const int q    = lane >> 4;       // quad
  const int b    = blockIdx.x >> 6;
  const int t0   = (blockIdx.x & 63) * BT;
  const int k0   = h * KH;

  // --- staging offsets: each half staged by its own 128 threads; 512 slots/tile ---
  // lds slot: [plane p][code][dg'] ; global group dg = dg' ^ code  (code 0..15)
  const int ptid = tid & 127;
  unsigned soff[4], slds[4];
#pragma unroll
  for (int i = 0; i < 4; ++i) {
    int flat = ptid + i * 128;             // 0..511
    int p    = flat >> 8;                  // plane 0/1 (256 slots each)
    int s    = flat & 255;
    int code = s >> 4;                     // 0..15
    int dgp  = s & 15;
    int dg   = dgp ^ code;
    soff[i] = (unsigned)(p * PLANE_B + code * 256 + dg * 16);
    slds[i] = (unsigned)(flat * 16);
  }
  const char* Eb = (const char*)Eplanes + (size_t)k0 * 256;  // half base (both planes)
  char* BsH = (char*)Bs + h * (2 * HTILE_B);                 // half's dbuf region

  // --- issue stage of buffer 0 (tile 0 of this half) ---
#pragma unroll
  for (int i = 0; i < 4; ++i)
    GLOAD_LDS(Eb + soff[i], BsH + slds[i]);

  // --- X -> registers, exact 2-way fp16 split (A-fragment layout) ---
  f16x8 A1[2][4], A2[2][4];
  {
    const float* xin = inp + (size_t)b * D * T_FULL + t0 + tw + c;
#pragma unroll
    for (int n = 0; n < 2; ++n)
#pragma unroll
      for (int dc = 0; dc < 4; ++dc) {
        f16x8 a1, a2;
#pragma unroll
        for (int j = 0; j < 8; ++j) {
          int d = dc * 32 + q * 8 + j;
          float x = xin[(size_t)d * T_FULL + n * 16];
          _Float16 h1 = (_Float16)x;
          _Float16 h2 = (_Float16)(x - (float)h1);
          a1[j] = h1; a2[j] = h2;
        }
        A1[n][dc] = a1; A2[n][dc] = a2;
      }
  }
  // --- ee -> LDS ---
#pragma unroll
  for (int i = tid; i < K; i += 256) ee_sh[i] = ee[i];
  __syncthreads();          // also drains initial staging (vmcnt(0) at barrier)

  float bv[2][4];
  int   bi[2][4];
#pragma unroll
  for (int n = 0; n < 2; ++n)
#pragma unroll
    for (int r = 0; r < 4; ++r) { bv[n][r] = 3.4e38f; bi[n][r] = 0; }

  for (int it = 0; it < NIT; ++it) {
    const int bb = it & 1;

    if (it) __syncthreads();   // protects buf reuse + drains prev staging

    // prefetch next tile of this half into buffer bb^1
    if (it != NIT - 1) {
      const char* gs = Eb + (size_t)(it + 1) * GTILE;
      char* ld = BsH + (bb ^ 1) * HTILE_B;
#pragma unroll
      for (int i = 0; i < 4; ++i)
        GLOAD_LDS(gs + soff[i], ld + slds[i]);
    }

    // compute on buffer bb: chained 3-term MFMA (R0-exact numerics)
    f32x4 acc[2];
    acc[0] = (f32x4){0.f, 0.f, 0.f, 0.f};
    acc[1] = (f32x4){0.f, 0.f, 0.f, 0.f};

    const char* Bp = BsH + bb * HTILE_B;
#pragma unroll
    for (int dc = 0; dc < 4; ++dc) {
      const int sw = ((dc * 4 + q) ^ c) * 16;       // de-swizzle
      const int ro = c * 256 + sw;
      f16x8 B1 = *(const f16x8*)(Bp + ro);
      f16x8 B2 = *(const f16x8*)(Bp + TPLANE + ro);
#pragma unroll
      for (int n = 0; n < 2; ++n) {
        f32x4 a = acc[n];
        a = MFMA(A1[n][dc], B1, a);   // 3-term split: x2*e2 ~2^-22, dropped
        a = MFMA(A1[n][dc], B2, a);
        a = MFMA(A2[n][dc], B1, a);
        acc[n] = a;
      }
    }

    // argmin update: dist = ee - 2*x.e ; codes ascending -> strict < = first occurrence
    const int code = k0 + it * KT + c;
    const float eev = ee_sh[code];
#pragma unroll
    for (int n = 0; n < 2; ++n)
#pragma unroll
      for (int r = 0; r < 4; ++r) {
        float dist = eev - acc[n][r];
        if (dist < bv[n][r]) { bv[n][r] = dist; bi[n][r] = code; }
      }
  }

  // --- cross-lane argmin over the 16 code-cols (tie -> smaller idx) ---
#pragma unroll
  for (int m = 1; m <= 8; m <<= 1)
#pragma unroll
    for (int n = 0; n < 2; ++n)
#pragma unroll
      for (int r = 0; r < 4; ++r) {
        float ov = __shfl_xor(bv[n][r], m, 64);
        int   oi = __shfl_xor(bi[n][r], m, 64);
        if (ov < bv[n][r] || (ov == bv[n][r] && oi < bi[n][r])) {
          bv[n][r] = ov; bi[n][r] = oi;
        }
      }
  if (c == 0) {
#pragma unroll
    for (int n = 0; n < 2; ++n)
#pragma unroll
      for (int r = 0; r < 4; ++r) {
        const int t = tw + n * 16 + q * 4 + r;
        mval[h][t] = bv[n][r];
        mi[h][t]   = bi[n][r];
      }
  }
  __syncthreads();

  // --- merge halves (half 0 has lower code indices; tie -> half 0 = first-min) ---
  if (tid < BT) {
    float v0 = mval[0][tid], v1 = mval[1][tid];
    int   ki = (v1 < v0) ? mi[1][tid] : mi[0][tid];
    midx[tid] = ki;
    out_idx[(size_t)b * T_FULL + t0 + tid] = (float)ki;
    atomicAdd(&counts[ki], 1u);
  }
  __syncthreads();

  // --- coalesced epilogue: thread=token (64), d-quarter per wave ---
  float lsum = 0.f;
  {
    const int t  = tid & 63;
    const int dq = tid >> 6;            // d-quarter: 32 d each
    const int kq = midx[t];
    const float* crow = cb + (size_t)kq * D + dq * 32;
    const float* xrow = inp + ((size_t)b * D + dq * 32) * T_FULL + t0 + t;
    float*       qrow = out_q + ((size_t)b * D + dq * 32) * T_FULL + t0 + t;
#pragma unroll
    for (int dd = 0; dd < 32; dd += 4) {
      float4 qv = *(const float4*)(crow + dd);
      float x0 = xrow[(size_t)(dd + 0) * T_FULL];
      float x1 = xrow[(size_t)(dd + 1) * T_FULL];
      float x2 = xrow[(size_t)(dd + 2) * T_FULL];
      float x3 = xrow[(size_t)(dd + 3) * T_FULL];
      float df;
      df = qv.x - x0; lsum = fmaf(df, df, lsum); qrow[(size_t)(dd + 0) * T_FULL] = qv.x;
      df = qv.y - x1; lsum = fmaf(df, df, lsum); qrow[(size_t)(dd + 1) * T_FULL] = qv.y;
      df = qv.z - x2; lsum = fmaf(df, df, lsum); qrow[(size_t)(dd + 2) * T_FULL] = qv.z;
      df = qv.w - x3; lsum = fmaf(df, df, lsum); qrow[(size_t)(dd + 3) * T_FULL] = qv.w;
    }
  }
#pragma unroll
  for (int o = 32; o > 0; o >>= 1) lsum += __shfl_down(lsum, o, 64);
  if (lane == 0) lred[w] = lsum;
  __syncthreads();
  if (tid == 0) {
    atomicAdd(loss_acc, lred[0] + lred[1] + lred[2] + lred[3]);
    __threadfence();                                   // publish before ticket
    unsigned ticket = atomicAdd(done, 1u);
    lastf = (ticket == NBLK - 1) ? 1 : 0;
  }
  __syncthreads();

  // --- last block: finalize loss + perplexity ---
  if (lastf) {
    __threadfence();
    float ent = 0.f;
#pragma unroll
    for (int i = tid; i < K; i += 256) {
      float cnt = (float)atomicAdd(&counts[i], 0u);    // coherent read
      float p = cnt * (1.0f / (float)NVEC);
      ent = fmaf(p, logf(p + 1e-10f), ent);
    }
#pragma unroll
    for (int o = 32; o > 0; o >>= 1) ent += __shfl_down(ent, o, 64);
    if (lane == 0) lred[w] = ent;
    __syncthreads();
    if (tid == 0) {
      float e = lred[0] + lred[1] + lred[2] + lred[3];
      float l = atomicAdd(loss_acc, 0.f);
      out[0]       = 0.25f * (l / (float)BDT);
      out[1 + BDT] = expf(-e);
    }
  }
}

extern "C" void kernel_launch(void* const* d_in, const int* in_sizes, int n_in,
                              void* d_out, int out_size, void* d_ws, size_t ws_size,
                              hipStream_t stream) {
  const float* inp = (const float*)d_in[0];   // [16,128,4096] fp32
  const float* cb  = (const float*)d_in[1];   // [1024,128] fp32
  float* out = (float*)d_out;                 // [loss | q(BDT) | perp | idx(B*T)]

  char* ws = (char*)d_ws;
  unsigned int* counts  = (unsigned int*)ws;                // 4 KB
  unsigned int* done    = (unsigned int*)(ws + 4096);
  float*        lossacc = (float*)(ws + 4160);
  float*        ee      = (float*)(ws + 8192);              // 4 KB
  _Float16*     E1      = (_Float16*)(ws + 12288);          // 256 KB
  _Float16*     E2      = (_Float16*)(ws + 12288 + PLANE_B);// 256 KB

  prep_kernel<<<K, 128, 0, stream>>>(cb, ee, E1, E2, counts, done, lossacc);
  vq_main<<<NBLK, 256, 0, stream>>>(inp, cb, ee, E1, counts, done, lossacc, out);
}